// Round 7
// baseline (32.477 us; speedup 1.0000x reference)
//
#include <hip/hip_runtime.h>

#define BB 4
#define SS 4096
#define HH 2048
#define KK 2048   // int(0.5 * 4096)

typedef float f4 __attribute__((ext_vector_type(4)));   // native vec for nontemporal builtin

// ---- scores: 16-lane row slices, LDS gate, 4-deep xor reduce ----
// Wave handles 4 rows: lane group g = lane>>4 owns row (row0+g), p = lane&15.
// Per chunk c (512 floats of the row), lane loads 8 dwordx4 at
// [c*128 + i*16 + p] (f4 units): 16 lanes/group cover 256 B contiguous per
// instruction -> full coalescing. Gate chunk read from LDS (4-way broadcast,
// conflict-free). fp64 FMA accumulation (exact products) as in R4.

__global__ void __launch_bounds__(256, 4)
scores_kernel(const float* __restrict__ hs,
              const float* __restrict__ gw,
              float* __restrict__ scores) {
    __shared__ f4 gls[512];               // 8 KB gate
    int t = threadIdx.x;
    const f4* g4 = reinterpret_cast<const f4*>(gw);
    gls[t]       = g4[t];
    gls[t + 256] = g4[t + 256];
    __syncthreads();

    int wave = t >> 6, lane = t & 63;
    int g = lane >> 4, p = lane & 15;
    int row = blockIdx.x * 16 + wave * 4 + g;
    const f4* r4 = reinterpret_cast<const f4*>(hs + (size_t)row * HH);

    f4 A[8], B[8];
#pragma unroll
    for (int i = 0; i < 8; ++i)
        A[i] = __builtin_nontemporal_load(&r4[i * 16 + p]);

    double acc0 = 0.0, acc1 = 0.0;
#pragma unroll
    for (int c = 0; c < 4; ++c) {
        if (c < 3) {
#pragma unroll
            for (int i = 0; i < 8; ++i)
                B[i] = __builtin_nontemporal_load(&r4[(c + 1) * 128 + i * 16 + p]);
        }
#pragma unroll
        for (int i = 0; i < 8; ++i) {
            f4 gg = gls[c * 128 + i * 16 + p];
            f4 aa = A[i];
            acc0 = fma((double)aa.x, (double)gg.x, acc0);
            acc1 = fma((double)aa.y, (double)gg.y, acc1);
            acc0 = fma((double)aa.z, (double)gg.z, acc0);
            acc1 = fma((double)aa.w, (double)gg.w, acc1);
        }
        if (c < 3) {
#pragma unroll
            for (int i = 0; i < 8; ++i) A[i] = B[i];   // SSA-renamed after unroll
        }
    }

    double s = acc0 + acc1;
    s += __shfl_xor(s, 8);
    s += __shfl_xor(s, 4);
    s += __shfl_xor(s, 2);
    s += __shfl_xor(s, 1);
    if (p == 0) scores[row] = (float)s;
}

// ---- topk: 4 waves per batch, DPP reduce, exact-exit fast path ----
// (byte-identical to R6 — proven)

__device__ __forceinline__ unsigned to_ord(float f) {
    unsigned u = __float_as_uint(f);
    return (u & 0x80000000u) ? ~u : (u | 0x80000000u);
}

__device__ __forceinline__ int dpp_wave_sum(int v) {
    v += __builtin_amdgcn_update_dpp(0, v, 0x111, 0xF, 0xF, true);  // row_shr:1
    v += __builtin_amdgcn_update_dpp(0, v, 0x112, 0xF, 0xF, true);  // row_shr:2
    v += __builtin_amdgcn_update_dpp(0, v, 0x114, 0xF, 0xF, true);  // row_shr:4
    v += __builtin_amdgcn_update_dpp(0, v, 0x118, 0xF, 0xF, true);  // row_shr:8
    v += __builtin_amdgcn_update_dpp(0, v, 0x142, 0xF, 0xF, true);  // row_bcast:15
    v += __builtin_amdgcn_update_dpp(0, v, 0x143, 0xF, 0xF, true);  // row_bcast:31
    return __builtin_amdgcn_readlane(v, 63);
}

__global__ void __launch_bounds__(256)
topk_mask_kernel(const float* __restrict__ scores, float* __restrict__ mask) {
    int b = blockIdx.x, t = threadIdx.x;
    int w = t >> 6, lane = t & 63;
    const f4* sc4 = reinterpret_cast<const f4*>(scores + b * SS);

    f4 v[4];
#pragma unroll
    for (int i = 0; i < 4; ++i) v[i] = sc4[t * 4 + i];

    unsigned ord[16];
#pragma unroll
    for (int i = 0; i < 4; ++i) {
        ord[4 * i + 0] = to_ord(v[i].x);
        ord[4 * i + 1] = to_ord(v[i].y);
        ord[4 * i + 2] = to_ord(v[i].z);
        ord[4 * i + 3] = to_ord(v[i].w);
    }

    __shared__ int wsum[2][4];
    __shared__ int tts[256];

    unsigned cur = 0u, thresh = 0u;
    bool exact = false;
    int par = 0;
    for (int bit = 31; bit >= 0; --bit) {
        unsigned cand = cur | (1u << bit);
        int c = 0;
#pragma unroll
        for (int i = 0; i < 16; ++i) c += (ord[i] >= cand) ? 1 : 0;
        int ws = dpp_wave_sum(c);
        if (lane == 0) wsum[par][w] = ws;
        __syncthreads();
        int total = wsum[par][0] + wsum[par][1] + wsum[par][2] + wsum[par][3];
        par ^= 1;
        if (total >= KK) cur = cand;
        if (total == KK) { exact = true; thresh = cand; break; }
    }

    f4* m4 = reinterpret_cast<f4*>(mask + b * SS);

    if (exact) {
#pragma unroll
        for (int i = 0; i < 4; ++i) {
            f4 m;
            m.x = (ord[4 * i + 0] >= thresh) ? 1.0f : 0.0f;
            m.y = (ord[4 * i + 1] >= thresh) ? 1.0f : 0.0f;
            m.z = (ord[4 * i + 2] >= thresh) ? 1.0f : 0.0f;
            m.w = (ord[4 * i + 3] >= thresh) ? 1.0f : 0.0f;
            m4[t * 4 + i] = m;
        }
        return;
    }

    // cold fallback: duplicates straddle the K boundary
    int cgl = 0, ttl = 0;
#pragma unroll
    for (int i = 0; i < 16; ++i) {
        cgl += (ord[i] > cur) ? 1 : 0;
        ttl += (ord[i] == cur) ? 1 : 0;
    }
    int cgw = dpp_wave_sum(cgl);
    if (lane == 0) wsum[0][w] = cgw;
    tts[t] = ttl;
    __syncthreads();
    int cg = wsum[0][0] + wsum[0][1] + wsum[0][2] + wsum[0][3];
    int r = KK - cg;
    if (t == 0) {
        int acc = 0;
        for (int i = 0; i < 256; ++i) { int x = tts[i]; tts[i] = acc; acc += x; }
    }
    __syncthreads();
    int pfx = tts[t];
#pragma unroll
    for (int i = 0; i < 4; ++i) {
        float mm[4];
#pragma unroll
        for (int j = 0; j < 4; ++j) {
            unsigned o = ord[4 * i + j];
            bool gt  = o > cur;
            bool tie = o == cur;
            mm[j] = (gt || (tie && pfx < r)) ? 1.0f : 0.0f;
            if (tie) ++pfx;
        }
        f4 m; m.x = mm[0]; m.y = mm[1]; m.z = mm[2]; m.w = mm[3];
        m4[t * 4 + i] = m;
    }
}

extern "C" void kernel_launch(void* const* d_in, const int* in_sizes, int n_in,
                              void* d_out, int out_size, void* d_ws, size_t ws_size,
                              hipStream_t stream) {
    const float* hs = (const float*)d_in[0];   // [B, S, H] fp32
    const float* gw = (const float*)d_in[1];   // [1, H] fp32
    float* out    = (float*)d_out;
    float* mask   = out;            // first output chunk  [B*S]
    float* scores = out + BB * SS;  // second output chunk [B*S]

    scores_kernel<<<BB * SS / 16, 256, 0, stream>>>(hs, gw, scores);
    topk_mask_kernel<<<BB, 256, 0, stream>>>(scores, mask);
}